// Round 19
// baseline (80.620 us; speedup 1.0000x reference)
//
#include <hip/hip_runtime.h>
#include <cstdint>
#include <cmath>

#define DEV __device__ __forceinline__

constexpr int SEL = 20;
constexpr int NSTEP2 = 10, NSTEP3 = 22, NSTEPS = 32;
constexpr int L2 = SEL + 1;   // 21 bits, group2
constexpr int L3 = SEL;       // 20 bits, group3
constexpr int FBE = 7;        // enumerated low bits
constexpr int FBS2 = L2 - FBE;   // 14
constexpr int FBS3 = L3 - FBE;   // 13
constexpr int BT = 128;          // kc block threads (2 waves, 2 chunks each)

typedef float v2f __attribute__((ext_vector_type(2)));

constexpr float K2E = 2.8853900817779268f;   // 2*log2(e)
constexpr float KE  = 1.4426950408889634f;   // log2(e)

struct Binom { unsigned v[22][22]; };
constexpr Binom make_binom() {
  Binom b{};
  for (int n = 0; n < 22; n++) {
    b.v[n][0] = 1;
    for (int k = 1; k < 22; k++)
      b.v[n][k] = (k > n) ? 0u : (k == n ? 1u : b.v[n - 1][k - 1] + b.v[n - 1][k]);
  }
  return b;
}
constexpr Binom BN_H = make_binom();
__device__ constexpr Binom BN = make_binom();

// compile-time chunk maps: 64-pattern chunks, popc-class-major
struct ChunkMap { int n; unsigned char cls[264]; unsigned short lbase[264]; };
template<int NB>
constexpr ChunkMap make_chunkmap() {
  ChunkMap m{}; int idx = 0;
  for (int k = 0; k <= NB; k++) {
    unsigned C = BN_H.v[NB][k];
    unsigned nch = (C + 63u) / 64u;
    for (unsigned i = 0; i < nch; i++) {
      m.cls[idx] = (unsigned char)k;
      m.lbase[idx] = (unsigned short)(i * 64);
      idx++;
    }
  }
  m.n = idx;
  return m;
}
__device__ constexpr ChunkMap CM2 = make_chunkmap<FBS2>();  // n = 264
__device__ constexpr ChunkMap CM3 = make_chunkmap<FBS3>();  // n = 138

// ---- ws layout (float indices) ----
constexpr int SUMS_STRIDE = 96;             // [0]=Se [1]=Sw [2..5]=Sws [6..9]=Swh [10+h*21+d]=GW1
constexpr int OFF_SUMS   = 0;               // 32 * 96 = 3072
constexpr int OFF_KEYB   = OFF_SUMS + NSTEPS * SUMS_STRIDE;  // 128
constexpr int OFF_CT     = OFF_KEYB + 128;  // int[32]
constexpr int OFF_CB     = OFF_CT + 32;     // uint[32]
constexpr int OFF_REP    = OFF_CB + 32;     // int[32]
constexpr int OFF_ZEND   = OFF_REP + 32;    // 3296

DEV float fast_tanh(float x) {
  float e = exp2f(x * K2E);
  return 1.0f - 2.0f * __builtin_amdgcn_rcpf(e + 1.0f);
}
DEV float fast_exp(float x) { return exp2f(x * KE); }
DEV void gatomic(float* p, float v) { unsafeAtomicAdd(p, v); }

DEV unsigned gosper(unsigned cmb) {
  unsigned u = cmb & (~cmb + 1u);
  unsigned v = cmb + u;
  return v | ((cmb ^ v) >> (1 + __ffs(u)));
}

DEV unsigned unrank_lds(const unsigned* sBN, int NB, int k, unsigned r) {
  unsigned cmb = 0; int kk = k;
  for (int bb = NB - 1; bb >= 0 && kk > 0; bb--) {
    unsigned cnt = sBN[bb * 22 + kk];
    if (r >= cnt) { cmb |= 1u << bb; r -= cnt; kk--; }
  }
  return cmb;
}

// wave64 sum via DPP (verified r12). Total lands in lane 63.
DEV float dppsum64(float x) {
  float f = x;
  f += __int_as_float(__builtin_amdgcn_update_dpp(0, __float_as_int(f), 0x111, 0xf, 0xf, false));
  f += __int_as_float(__builtin_amdgcn_update_dpp(0, __float_as_int(f), 0x112, 0xf, 0xf, false));
  f += __int_as_float(__builtin_amdgcn_update_dpp(0, __float_as_int(f), 0x114, 0xf, 0xf, false));
  f += __int_as_float(__builtin_amdgcn_update_dpp(0, __float_as_int(f), 0x118, 0xf, 0xf, false));
  f += __int_as_float(__builtin_amdgcn_update_dpp(0, __float_as_int(f), 0x142, 0xa, 0xf, false));
  f += __int_as_float(__builtin_amdgcn_update_dpp(0, __float_as_int(f), 0x143, 0xc, 0xf, false));
  return f;
}

// =================== Kernel Z: init (1 block) ===================
__global__ __launch_bounds__(256) void kz(const float* p0, const float* sel,
                   const float* W1_2, const float* b1_2,
                   const float* W1_3, const float* b1_3, float* ws) {
  int tx = threadIdx.x;
  __shared__ int sc[NSTEPS];
  for (int i = tx; i < OFF_ZEND; i += 256) ws[i] = 0.0f;
  __syncthreads();
  if (tx < NSTEPS) {
    int t = tx;
    int g = (t < NSTEP2) ? 0 : 1;
    int L = g ? L3 : L2;
    const float* sbase = sel + (g ? (NSTEP2 * L2 + (t - NSTEP2) * L3) : t * L2);
    unsigned cb = 0; int c = 0;
    for (int d = 0; d < L; d++)
      if (sbase[d] > 0.5f) { cb |= 1u << d; c++; }
    sc[t] = c;
    ((int*)ws)[OFF_CT + t] = c;
    ((unsigned*)ws)[OFF_CB + t] = cb;
    const float* W1 = g ? W1_3 : W1_2;
    const float* b1 = g ? b1_3 : b1_2;
    for (int h = 0; h < 4; h++) {
      float s = b1[h];
      for (int d = 0; d < L; d++)
        if ((cb >> d) & 1) s += W1[h * (L + 1) + 1 + d];
      ws[OFF_KEYB + t * 4 + h] = s;
    }
  }
  __syncthreads();
  if (tx < NSTEPS) {
    int r = tx;
    int start = (tx == 0) ? 0 : ((tx < NSTEP2) ? 1 : NSTEP2);
    for (int u = start; u < tx; u++)
      if (sc[u] == sc[tx]) { r = u; break; }
    ((int*)ws)[OFF_REP + tx] = r;
  }
}

// =================== Kernel C: self-sufficient, dual-chunk waves ===================
constexpr int KCB2 = 66;   // 264 chunks / 4 per block
constexpr int KCB3 = 35;   // ceil(138/4)
constexpr int KC_BLOCKS = NSTEP2 * KCB2 + NSTEP3 * KCB3;   // 1430

template<int LL>
DEV void kc_work(int t, int sub, float pval,
                 const float* W1, const float* b1, const float* W2, const float* b2,
                 float* ws, float4* tabL, unsigned* sBN, float* sS) {
  constexpr int FS = LL - FBE;               // structural bit count: 14 / 13
  constexpr int NS1 = 1 << (LL - 14);
  constexpr int NS1M = NS1 - 1;
  const ChunkMap& CM = (LL == 21) ? CM2 : CM3;
  const int CMN = CM.n;
  int tx = threadIdx.x;
  int c = ((const int*)ws)[OFF_CT + t];
  // block-level early exit (uniform)
  bool any = false;
  for (int i = 0; i < 4; i++) {
    int ci = sub * 4 + i;
    if (ci < CMN) {
      int ce = c - (int)CM.cls[ci];
      if (ce >= 0 && ce <= FBE) any = true;
    }
  }
  if (!any) return;
  // stage BN + build tabs (direct from weights; ~150 ops/thread)
  {
    const unsigned* bnf = &BN.v[0][0];
    for (int i = tx; i < 484; i += BT) sBN[i] = bnf[i];
    for (int i = tx; i < 256 + NS1; i += BT) {
      float4 v; float* vp = (float*)&v;
      if (i < 128) {
        int e = i;
        for (int h = 0; h < 4; h++) {
          float s = 0;
          for (int j = 0; j < 7; j++) if ((e >> j) & 1) s += W1[h * (LL + 1) + 1 + j];
          vp[h] = exp2f(K2E * s);
        }
      } else if (i < 256) {
        int e = i - 128;
        for (int h = 0; h < 4; h++) {
          float s = b1[h] + pval * W1[h * (LL + 1)];
          for (int j = 0; j < 7; j++) if ((e >> j) & 1) s += W1[h * (LL + 1) + 1 + 7 + j];
          vp[h] = s;
        }
      } else {
        int e = i - 256;
        for (int h = 0; h < 4; h++) {
          float s = 0;
          for (int j = 0; j < LL - 14; j++) if ((e >> j) & 1) s += W1[h * (LL + 1) + 1 + 14 + j];
          vp[h] = s;
        }
      }
      tabL[i] = v;
    }
    if (tx < SUMS_STRIDE) sS[tx] = 0.0f;
  }
  __syncthreads();
  const float4* tabEX = tabL;
  const float4* tabS0 = tabL + 128;
  const float4* tabS1 = tabL + 256;
  int lane = tx & 63, wid = tx >> 6;

  float w0 = W2[0], w1 = W2[1], w2 = W2[2], w3 = W2[3];
  float W0 = b2[0] + w0 + w1 + w2 + w3;
  float m0 = -2.0f * w0, m1 = -2.0f * w1, m2 = -2.0f * w2, m3 = -2.0f * w3;
  float M0 = 4.0f * w0, M1 = 4.0f * w1, M2 = 4.0f * w2, M3 = 4.0f * w3;

  // wave-shared accumulators
  float aE = 0.0f, aW = 0.0f;
  v2f ORa = {0, 0}, ORb = {0, 0};
#define G_DECL(k) v2f g##k##a = {0, 0}, g##k##b = {0, 0};
  G_DECL(0) G_DECL(1) G_DECL(2) G_DECL(3) G_DECL(4) G_DECL(5) G_DECL(6)
#undef G_DECL

#define DO_CHUNK(id) \
  v2f cQa##id = {0, 0}, cQb##id = {0, 0}; unsigned pat##id = 0; \
  { int ci = sub * 4 + wid * 2 + id; \
    if (ci < CMN) { \
      int k = (int)CM.cls[ci]; \
      int ce = c - k; \
      if (ce >= 0 && ce <= FBE) { \
        unsigned Ck = sBN[FS * 22 + k]; \
        unsigned myr = (unsigned)CM.lbase[ci] + (unsigned)lane; \
        float valid = (myr < Ck) ? 1.0f : 0.0f; \
        unsigned pr = (myr < Ck) ? myr : (Ck - 1u); \
        unsigned pp = unrank_lds(sBN, FS, k, pr); \
        pat##id = pp; \
        float4 vS0 = tabS0[pp & 127]; \
        float4 vS1 = tabS1[(pp >> 7) & NS1M]; \
        float E0 = exp2f(K2E * (vS0.x + vS1.x)); \
        float E1 = exp2f(K2E * (vS0.y + vS1.y)); \
        float E2 = exp2f(K2E * (vS0.z + vS1.z)); \
        float E3 = exp2f(K2E * (vS0.w + vS1.w)); \
        int trip = (int)sBN[FBE * 22 + ce]; \
        unsigned ivs = (1u << ce) - 1u; \
        float4 tE = tabEX[ivs & 127]; \
        _Pragma("unroll 1") \
        for (int kk = 0; kk < trip; kk++) { \
          float4 cur = tE; \
          unsigned ivc = ivs; \
          ivs = gosper(ivs); \
          tE = tabEX[ivs & 127]; \
          float r0 = __builtin_amdgcn_rcpf(fmaf(cur.x, E0, 1.0f)); \
          float r1 = __builtin_amdgcn_rcpf(fmaf(cur.y, E1, 1.0f)); \
          float r2 = __builtin_amdgcn_rcpf(fmaf(cur.z, E2, 1.0f)); \
          float r3 = __builtin_amdgcn_rcpf(fmaf(cur.w, E3, 1.0f)); \
          float outv = W0; \
          outv = fmaf(m0, r0, outv); outv = fmaf(m1, r1, outv); \
          outv = fmaf(m2, r2, outv); outv = fmaf(m3, r3, outv); \
          float e = exp2f(KE * outv) * valid; \
          outv *= valid; \
          float u0 = fmaf(-r0, r0, r0), u1 = fmaf(-r1, r1, r1); \
          float u2 = fmaf(-r2, r2, r2), u3 = fmaf(-r3, r3, r3); \
          float q0 = outv * (M0 * u0), q1 = outv * (M1 * u1); \
          float q2 = outv * (M2 * u2), q3 = outv * (M3 * u3); \
          v2f qa = {q0, q1}, qb = {q2, q3}; \
          aE += e; aW += outv; \
          cQa##id += qa; cQb##id += qb; \
          ORa += (v2f){outv * r0, outv * r1}; \
          ORb += (v2f){outv * r2, outv * r3}; \
          if (ivc & 1u)  { g0a += qa; g0b += qb; } \
          if (ivc & 2u)  { g1a += qa; g1b += qb; } \
          if (ivc & 4u)  { g2a += qa; g2b += qb; } \
          if (ivc & 8u)  { g3a += qa; g3b += qb; } \
          if (ivc & 16u) { g4a += qa; g4b += qb; } \
          if (ivc & 32u) { g5a += qa; g5b += qb; } \
          if (ivc & 64u) { g6a += qa; g6b += qb; } \
        } \
      } } }
  DO_CHUNK(0)
  DO_CHUNK(1)
#undef DO_CHUNK

  v2f aQa = cQa0 + cQa1, aQb = cQb0 + cQb1;
  v2f aWHa = {aW - 2.0f * ORa.x, aW - 2.0f * ORa.y};
  v2f aWHb = {aW - 2.0f * ORb.x, aW - 2.0f * ORb.y};

  float rr;
  rr = dppsum64(aE); if (lane == 63 && rr != 0.0f) atomicAdd(&sS[0], rr);
  rr = dppsum64(aW); if (lane == 63 && rr != 0.0f) atomicAdd(&sS[1], rr);
  rr = dppsum64(aQa.x); if (lane == 63 && rr != 0.0f) atomicAdd(&sS[2], rr);
  rr = dppsum64(aQa.y); if (lane == 63 && rr != 0.0f) atomicAdd(&sS[3], rr);
  rr = dppsum64(aQb.x); if (lane == 63 && rr != 0.0f) atomicAdd(&sS[4], rr);
  rr = dppsum64(aQb.y); if (lane == 63 && rr != 0.0f) atomicAdd(&sS[5], rr);
  rr = dppsum64(aWHa.x); if (lane == 63 && rr != 0.0f) atomicAdd(&sS[6], rr);
  rr = dppsum64(aWHa.y); if (lane == 63 && rr != 0.0f) atomicAdd(&sS[7], rr);
  rr = dppsum64(aWHb.x); if (lane == 63 && rr != 0.0f) atomicAdd(&sS[8], rr);
  rr = dppsum64(aWHb.y); if (lane == 63 && rr != 0.0f) atomicAdd(&sS[9], rr);
#define GF(k) { \
  rr = dppsum64(g##k##a.x); if (lane == 63 && rr != 0.0f) atomicAdd(&sS[10 + 0 * 21 + k], rr); \
  rr = dppsum64(g##k##a.y); if (lane == 63 && rr != 0.0f) atomicAdd(&sS[10 + 1 * 21 + k], rr); \
  rr = dppsum64(g##k##b.x); if (lane == 63 && rr != 0.0f) atomicAdd(&sS[10 + 2 * 21 + k], rr); \
  rr = dppsum64(g##k##b.y); if (lane == 63 && rr != 0.0f) atomicAdd(&sS[10 + 3 * 21 + k], rr); }
  GF(0) GF(1) GF(2) GF(3) GF(4) GF(5) GF(6)
#undef GF
#pragma unroll
  for (int j = 0; j < 14; j++) {
    if (j < FS) {
      float b0f = (float)((pat0 >> j) & 1u);
      float b1f = (float)((pat1 >> j) & 1u);
      float vax = fmaf(b0f, cQa0.x, b1f * cQa1.x);
      float vay = fmaf(b0f, cQa0.y, b1f * cQa1.y);
      float vbx = fmaf(b0f, cQb0.x, b1f * cQb1.x);
      float vby = fmaf(b0f, cQb0.y, b1f * cQb1.y);
      rr = dppsum64(vax); if (lane == 63 && rr != 0.0f) atomicAdd(&sS[10 + 0 * 21 + FBE + j], rr);
      rr = dppsum64(vay); if (lane == 63 && rr != 0.0f) atomicAdd(&sS[10 + 1 * 21 + FBE + j], rr);
      rr = dppsum64(vbx); if (lane == 63 && rr != 0.0f) atomicAdd(&sS[10 + 2 * 21 + FBE + j], rr);
      rr = dppsum64(vby); if (lane == 63 && rr != 0.0f) atomicAdd(&sS[10 + 3 * 21 + FBE + j], rr);
    }
  }
  __syncthreads();
  if (tx < SUMS_STRIDE) {
    float v = sS[tx];
    if (v != 0.0f) gatomic(&ws[OFF_SUMS + t * SUMS_STRIDE + tx], v);
  }
}

__global__ __launch_bounds__(BT) void kc(
    const float* p0,
    const float* W1_2, const float* b1_2, const float* W2_2, const float* b2_2,
    const float* W1_3, const float* b1_3, const float* W2_3, const float* b2_3,
    float* ws) {
  __shared__ float4 tabL[384];
  __shared__ unsigned sBN[484];
  __shared__ float sS[SUMS_STRIDE];
  int b = blockIdx.x;
  int t, sub;
  if (b < NSTEP2 * KCB2) { t = b / KCB2; sub = b % KCB2; }
  else { int b3 = b - NSTEP2 * KCB2; t = NSTEP2 + b3 / KCB3; sub = b3 % KCB3; }
  if (((const int*)ws)[OFF_REP + t] != t) return;   // only representative steps
  if (t < NSTEP2) {
    float pval = (t == 0) ? p0[0] : 0.0f;
    kc_work<21>(t, sub, pval, W1_2, b1_2, W2_2, b2_2, ws, tabL, sBN, sS);
  } else {
    kc_work<20>(t, sub, 0.0f, W1_3, b1_3, W2_3, b2_3, ws, tabL, sBN, sS);
  }
}

// =================== Kernel D: p-chain + finalize gradient outputs ===================
__global__ __launch_bounds__(256) void kd(const float* p0in,
                   const float* W1_2, const float* b1_2, const float* W2_2, const float* b2_2,
                   const float* W1_3, const float* b1_3, const float* W2_3, const float* b2_3,
                   const float* ws, float* out) {
  __shared__ float sS[NSTEPS * SUMS_STRIDE];   // 12 KB
  __shared__ float sKEYB[128], sW1c0[8], sW2[8], sB2[2];
  __shared__ float sk_s[NSTEPS][4], hk_s[NSTEPS][4], pp_s[NSTEPS], s0i_s[NSTEPS];
  __shared__ int sREP[NSTEPS];
  int tx = threadIdx.x;
  for (int i = tx; i < NSTEPS * SUMS_STRIDE; i += 256) sS[i] = ws[OFF_SUMS + i];
  for (int i = tx; i < 128; i += 256) sKEYB[i] = ws[OFF_KEYB + i];
  if (tx < NSTEPS) sREP[tx] = ((const int*)ws)[OFF_REP + tx];
  if (tx < 4) {
    sW1c0[tx]     = W1_2[tx * (L2 + 1)];
    sW1c0[4 + tx] = W1_3[tx * (L3 + 1)];
    sW2[tx]     = W2_2[tx];
    sW2[4 + tx] = W2_3[tx];
  }
  if (tx == 0) { sB2[0] = b2_2[0]; sB2[1] = b2_3[0]; }
  __syncthreads();
  if (tx == 0) {
    float p = p0in[0];
    out[0] = p;
    for (int t = 0; t < NSTEPS; t++) {
      int g = (t < NSTEP2) ? 0 : 1;
      pp_s[t] = p;
      float outk = sB2[g];
      for (int h = 0; h < 4; h++)
        outk += sW2[g * 4 + h] * fast_tanh(sKEYB[t * 4 + h] + p * sW1c0[g * 4 + h]);
      float Se = sS[sREP[t] * SUMS_STRIDE + 0];
      p = fast_exp(outk) / Se;
      out[1 + t] = p;
    }
  }
  __syncthreads();
  if (tx < NSTEPS) {
    int t = tx; int g = (t < NSTEP2) ? 0 : 1;
    float p = pp_s[t];
    s0i_s[t] = 1.0f / sS[sREP[t] * SUMS_STRIDE + 0];
    for (int h = 0; h < 4; h++) {
      float hk = fast_tanh(sKEYB[t * 4 + h] + p * sW1c0[g * 4 + h]);
      hk_s[t][h] = hk;
      sk_s[t][h] = (1.0f - hk * hk) * sW2[g * 4 + h];
    }
  }
  __syncthreads();
  const unsigned* cbp = (const unsigned*)ws;
  for (int o = 33 + tx; o < 223; o += blockDim.x) {
    float val = 0.0f;
    if (o < 130) {
      if (o < 121) {
        int e = o - 33; int h = e / 22, d = e % 22;
        for (int t = 0; t < NSTEP2; t++) {
          int rp = sREP[t];
          float xk = (d == 0) ? pp_s[t] : (float)((cbp[OFF_CB + t] >> (d - 1)) & 1);
          float gs = (d == 0) ? pp_s[t] * sS[rp * SUMS_STRIDE + 2 + h]
                              : sS[rp * SUMS_STRIDE + 10 + h * 21 + (d - 1)];
          val += sk_s[t][h] * xk - gs * s0i_s[t];
        }
      } else if (o < 125) { int h = o - 121;
        for (int t = 0; t < NSTEP2; t++) val += sk_s[t][h] - sS[sREP[t] * SUMS_STRIDE + 2 + h] * s0i_s[t];
      } else if (o < 129) { int h = o - 125;
        for (int t = 0; t < NSTEP2; t++) val += hk_s[t][h] - sS[sREP[t] * SUMS_STRIDE + 6 + h] * s0i_s[t];
      } else {
        for (int t = 0; t < NSTEP2; t++) val += 1.0f - sS[sREP[t] * SUMS_STRIDE + 1] * s0i_s[t];
      }
    } else {
      if (o < 214) {
        int e = o - 130; int h = e / 21, d = e % 21;
        for (int t = NSTEP2; t < NSTEPS; t++) {
          int rp = sREP[t];
          float xk = (d == 0) ? pp_s[t] : (float)((cbp[OFF_CB + t] >> (d - 1)) & 1);
          float gs = (d == 0) ? pp_s[t] * sS[rp * SUMS_STRIDE + 2 + h]
                              : sS[rp * SUMS_STRIDE + 10 + h * 21 + (d - 1)];
          val += sk_s[t][h] * xk - gs * s0i_s[t];
        }
      } else if (o < 218) { int h = o - 214;
        for (int t = NSTEP2; t < NSTEPS; t++) val += sk_s[t][h] - sS[sREP[t] * SUMS_STRIDE + 2 + h] * s0i_s[t];
      } else if (o < 222) { int h = o - 218;
        for (int t = NSTEP2; t < NSTEPS; t++) val += hk_s[t][h] - sS[sREP[t] * SUMS_STRIDE + 6 + h] * s0i_s[t];
      } else {
        for (int t = NSTEP2; t < NSTEPS; t++) val += 1.0f - sS[sREP[t] * SUMS_STRIDE + 1] * s0i_s[t];
      }
    }
    out[o] = val;
  }
}

extern "C" void kernel_launch(void* const* d_in, const int* in_sizes, int n_in,
                              void* d_out, int out_size, void* d_ws, size_t ws_size,
                              hipStream_t stream) {
  const float* p0   = (const float*)d_in[0];
  const float* sel  = (const float*)d_in[1];
  const float* W1_2 = (const float*)d_in[2]; const float* b1_2 = (const float*)d_in[3];
  const float* W2_2 = (const float*)d_in[4]; const float* b2_2 = (const float*)d_in[5];
  const float* W1_3 = (const float*)d_in[6]; const float* b1_3 = (const float*)d_in[7];
  const float* W2_3 = (const float*)d_in[8]; const float* b2_3 = (const float*)d_in[9];
  float* out = (float*)d_out;
  float* ws  = (float*)d_ws;
  hipLaunchKernelGGL(kz, dim3(1), dim3(256), 0, stream,
                     p0, sel, W1_2, b1_2, W1_3, b1_3, ws);
  hipLaunchKernelGGL(kc, dim3(KC_BLOCKS), dim3(BT), 0, stream, p0,
                     W1_2, b1_2, W2_2, b2_2, W1_3, b1_3, W2_3, b2_3, ws);
  hipLaunchKernelGGL(kd, dim3(1), dim3(256), 0, stream, p0,
                     W1_2, b1_2, W2_2, b2_2, W1_3, b1_3, W2_3, b2_3, ws, out);
}

// Round 20
// 68.425 us; speedup vs baseline: 1.1782x; 1.1782x over previous
//
#include <hip/hip_runtime.h>
#include <cstdint>
#include <cmath>

#define DEV __device__ __forceinline__

constexpr int SEL = 20;
constexpr int NSTEP2 = 10, NSTEP3 = 22, NSTEPS = 32;
constexpr int L2 = SEL + 1;   // 21 bits, group2
constexpr int L3 = SEL;       // 20 bits, group3
constexpr int FBE = 7;        // enumerated low bits
constexpr int FBS2 = L2 - FBE;   // 14
constexpr int FBS3 = L3 - FBE;   // 13
constexpr int BT = 128;          // kc block threads (2 waves)

typedef float v2f __attribute__((ext_vector_type(2)));

constexpr float K2E = 2.8853900817779268f;   // 2*log2(e)
constexpr float KE  = 1.4426950408889634f;   // log2(e)

struct Binom { unsigned v[22][22]; };
constexpr Binom make_binom() {
  Binom b{};
  for (int n = 0; n < 22; n++) {
    b.v[n][0] = 1;
    for (int k = 1; k < 22; k++)
      b.v[n][k] = (k > n) ? 0u : (k == n ? 1u : b.v[n - 1][k - 1] + b.v[n - 1][k]);
  }
  return b;
}
constexpr Binom BN_H = make_binom();
__device__ constexpr Binom BN = make_binom();

constexpr unsigned ceil64u(unsigned x) { return (x + 63u) & ~63u; }
constexpr int padded_count(int NB) {
  int s = 0;
  for (int k = 0; k <= NB; k++) s += (int)ceil64u(BN_H.v[NB][k]);
  return s;
}
constexpr int NPAT2P = padded_count(FBS2);  // 16896
constexpr int NPAT3P = padded_count(FBS3);  // 8832

// ---- ws layout (float indices) ----
constexpr int SUMS_STRIDE = 96;             // [0]=Se [1]=Sw [2..5]=Sws [6..9]=Swh [10+h*21+d]=GW1
constexpr int OFF_SUMS   = 0;               // 32 * 96 = 3072
constexpr int OFF_KEYB   = OFF_SUMS + NSTEPS * SUMS_STRIDE;  // 128
constexpr int OFF_CT     = OFF_KEYB + 128;  // int[32]
constexpr int OFF_CB     = OFF_CT + 32;     // uint[32]
constexpr int OFF_REP    = OFF_CB + 32;     // int[32]
constexpr int OFF_ZEND   = OFF_REP + 32;    // zero range end = 3296 (16B aligned)
constexpr int OFF_TABS   = OFF_ZEND;        // float4[3*384] = 4608 floats
constexpr int OFF_PAT2   = OFF_TABS + 3 * 384 * 4;          // uint[NPAT2P]
constexpr int OFF_PAT3   = OFF_PAT2 + NPAT2P;               // uint[NPAT3P]

DEV float fast_tanh(float x) {
  float e = exp2f(x * K2E);
  return 1.0f - 2.0f * __builtin_amdgcn_rcpf(e + 1.0f);
}
DEV float fast_exp(float x) { return exp2f(x * KE); }
DEV void gatomic(float* p, float v) { unsafeAtomicAdd(p, v); }

DEV unsigned gosper(unsigned cmb) {
  unsigned u = cmb & (~cmb + 1u);
  unsigned v = cmb + u;
  return v | ((cmb ^ v) >> (1 + __ffs(u)));
}

// wave64 sum via DPP (verified r12). Total lands in lane 63.
DEV float dppsum64(float x) {
  float f = x;
  f += __int_as_float(__builtin_amdgcn_update_dpp(0, __float_as_int(f), 0x111, 0xf, 0xf, false));
  f += __int_as_float(__builtin_amdgcn_update_dpp(0, __float_as_int(f), 0x112, 0xf, 0xf, false));
  f += __int_as_float(__builtin_amdgcn_update_dpp(0, __float_as_int(f), 0x114, 0xf, 0xf, false));
  f += __int_as_float(__builtin_amdgcn_update_dpp(0, __float_as_int(f), 0x118, 0xf, 0xf, false));
  f += __int_as_float(__builtin_amdgcn_update_dpp(0, __float_as_int(f), 0x142, 0xa, 0xf, false));
  f += __int_as_float(__builtin_amdgcn_update_dpp(0, __float_as_int(f), 0x143, 0xc, 0xf, false));
  return f;
}

// =================== Kernel Z: init + rep map + 3 tab sets + pattern tables ===================
// block 0: init; blocks 1..3: tab sets (0: g2@p0, 1: g2@0, 2: g3@0); blocks 4..: patterns
__global__ void kz(const float* p0, const float* sel,
                   const float* W1_2, const float* b1_2,
                   const float* W1_3, const float* b1_3, float* ws) {
  int tx = threadIdx.x;
  int b = blockIdx.x;
  if (b == 0) {
    __shared__ int sc[NSTEPS];
    for (int i = tx; i < OFF_ZEND; i += blockDim.x) ws[i] = 0.0f;
    __syncthreads();
    if (tx < NSTEPS) {
      int t = tx;
      int g = (t < NSTEP2) ? 0 : 1;
      int L = g ? L3 : L2;
      const float* sbase = sel + (g ? (NSTEP2 * L2 + (t - NSTEP2) * L3) : t * L2);
      unsigned cb = 0; int c = 0;
      for (int d = 0; d < L; d++)
        if (sbase[d] > 0.5f) { cb |= 1u << d; c++; }
      sc[t] = c;
      ((int*)ws)[OFF_CT + t] = c;
      ((unsigned*)ws)[OFF_CB + t] = cb;
      const float* W1 = g ? W1_3 : W1_2;
      const float* b1 = g ? b1_3 : b1_2;
      for (int h = 0; h < 4; h++) {
        float s = b1[h];
        for (int d = 0; d < L; d++)
          if ((cb >> d) & 1) s += W1[h * (L + 1) + 1 + d];
        ws[OFF_KEYB + t * 4 + h] = s;
      }
    }
    __syncthreads();
    if (tx < NSTEPS) {
      int r = tx;
      int start = (tx == 0) ? 0 : ((tx < NSTEP2) ? 1 : NSTEP2);
      for (int u = start; u < tx; u++)
        if (sc[u] == sc[tx]) { r = u; break; }
      ((int*)ws)[OFF_REP + tx] = r;
    }
  } else if (b <= 3) {
    int set = b - 1;
    int LL = (set < 2) ? L2 : L3;
    const float* W1 = (set < 2) ? W1_2 : W1_3;
    const float* b1 = (set < 2) ? b1_2 : b1_3;
    float pval = (set == 0) ? p0[0] : 0.0f;
    int NS1 = 1 << (LL - 14);
    float4* gt = (float4*)(ws + OFF_TABS) + set * 384;
    for (int i = tx; i < 256 + NS1; i += 256) {
      float4 v;
      float* vp = (float*)&v;
      if (i < 128) {
        int e = i;
        for (int h = 0; h < 4; h++) {
          float s = 0;
          for (int j = 0; j < 7; j++) if ((e >> j) & 1) s += W1[h * (LL + 1) + 1 + j];
          vp[h] = exp2f(K2E * s);
        }
      } else if (i < 256) {
        int e = i - 128;
        for (int h = 0; h < 4; h++) {
          float s = b1[h] + pval * W1[h * (LL + 1)];
          for (int j = 0; j < 7; j++) if ((e >> j) & 1) s += W1[h * (LL + 1) + 1 + 7 + j];
          vp[h] = s;
        }
      } else {
        int e = i - 256;
        for (int h = 0; h < 4; h++) {
          float s = 0;
          for (int j = 0; j < LL - 14; j++) if ((e >> j) & 1) s += W1[h * (LL + 1) + 1 + 14 + j];
          vp[h] = s;
        }
      }
      gt[i] = v;
    }
  } else {
    int r = (b - 4) * 256 + tx;
    if (r >= NPAT2P + NPAT3P) return;
    int NB, rr, off;
    if (r < NPAT2P) { NB = FBS2; rr = r; off = OFF_PAT2; }
    else            { NB = FBS3; rr = r - NPAT2P; off = OFF_PAT3; }
    unsigned pat = 0xFFFFFFFFu;   // sentinel (padding)
    unsigned base = 0;
    for (int kk = 0; kk <= NB; kk++) {
      unsigned csz = BN.v[NB][kk];
      unsigned psz = (csz + 63u) & ~63u;
      if ((unsigned)rr < base + psz) {
        unsigned local = (unsigned)rr - base;
        if (local < csz) {
          unsigned p2 = 0; int k2 = kk;
          for (int bb = NB - 1; bb >= 0 && k2 > 0; bb--) {
            unsigned cnt = BN.v[bb][k2];
            if (local >= cnt) { p2 |= 1u << bb; local -= cnt; k2--; }
          }
          pat = p2;
        }
        break;
      }
      base += psz;
    }
    ((unsigned*)ws)[off + rr] = pat;
  }
}

// =================== Kernel C: per-representative-class, LDS-staged epilogue ===================
constexpr int KC_B2 = NPAT2P / BT;   // 132
constexpr int KC_B3 = NPAT3P / BT;   // 69
constexpr int KC_BLOCKS = NSTEP2 * KC_B2 + NSTEP3 * KC_B3;

template<int LL>
DEV void kc_work(int t, int sub, int set,
                 const float* W2, const float* b2,
                 float* ws, float4* tabL, float* sS) {
  constexpr int FS = LL - FBE;
  constexpr int NS1 = 1 << (LL - 14);
  constexpr int NS1M = NS1 - 1;
  int tx = threadIdx.x;
  int c = ((const int*)ws)[OFF_CT + t];
  const unsigned* pats = ((const unsigned*)ws) + (LL == 21 ? OFF_PAT2 : OFF_PAT3);
  int pcF = __popc(pats[sub * BT]);        // wave-leader popcounts always valid (64-aligned classes)
  int pcL = __popc(pats[sub * BT + 64]);
  if (c < pcF || c - pcL > FBE) return;
  // load precomputed tabs (global, L2-hot) into LDS
  const float4* gt = (const float4*)(ws + OFF_TABS) + set * 384;
  for (int i = tx; i < 256 + NS1; i += BT) tabL[i] = gt[i];
  if (tx < SUMS_STRIDE) sS[tx] = 0.0f;
  __syncthreads();
  const float4* tabEX = tabL;
  const float4* tabS0 = tabL + 128;
  const float4* tabS1 = tabL + 256;

  unsigned pat = pats[sub * BT + tx];
  int ce = c - __popc(pat);
  int ce_s = __builtin_amdgcn_readfirstlane(ce);
  int trip = (ce_s >= 0 && ce_s <= FBE) ? (int)BN.v[FBE][ce_s] : 0;
  if (trip > 0) {
    float valid = (ce == ce_s) ? 1.0f : 0.0f;
    float4 vS0 = tabS0[pat & 127];
    float4 vS1 = tabS1[(pat >> 7) & NS1M];
    float E0 = exp2f(K2E * (vS0.x + vS1.x));
    float E1 = exp2f(K2E * (vS0.y + vS1.y));
    float E2 = exp2f(K2E * (vS0.z + vS1.z));
    float E3 = exp2f(K2E * (vS0.w + vS1.w));
    float w0 = W2[0], w1 = W2[1], w2 = W2[2], w3 = W2[3];
    float W0 = b2[0] + w0 + w1 + w2 + w3;
    float m0 = -2.0f * w0, m1 = -2.0f * w1, m2 = -2.0f * w2, m3 = -2.0f * w3;
    float M0 = 4.0f * w0, M1 = 4.0f * w1, M2 = 4.0f * w2, M3 = 4.0f * w3;

    float aE = 0.0f, aW = 0.0f;
    v2f aQa = {0, 0}, aQb = {0, 0}, ORa = {0, 0}, ORb = {0, 0};
#define G_DECL(k) v2f g##k##a = {0, 0}, g##k##b = {0, 0};
    G_DECL(0) G_DECL(1) G_DECL(2) G_DECL(3) G_DECL(4) G_DECL(5) G_DECL(6)
#undef G_DECL

    unsigned ivs = (1u << ce_s) - 1u;
    float4 tE = tabEX[ivs & 127];
#pragma unroll 1
    for (int k = 0; k < trip; k++) {
      float4 cur = tE;
      unsigned ivc = ivs;
      ivs = gosper(ivs);
      tE = tabEX[ivs & 127];
      float r0 = __builtin_amdgcn_rcpf(fmaf(cur.x, E0, 1.0f));
      float r1 = __builtin_amdgcn_rcpf(fmaf(cur.y, E1, 1.0f));
      float r2 = __builtin_amdgcn_rcpf(fmaf(cur.z, E2, 1.0f));
      float r3 = __builtin_amdgcn_rcpf(fmaf(cur.w, E3, 1.0f));
      float outv = W0;
      outv = fmaf(m0, r0, outv); outv = fmaf(m1, r1, outv);
      outv = fmaf(m2, r2, outv); outv = fmaf(m3, r3, outv);
      float e = exp2f(KE * outv) * valid;
      outv *= valid;
      float u0 = fmaf(-r0, r0, r0), u1 = fmaf(-r1, r1, r1);
      float u2 = fmaf(-r2, r2, r2), u3 = fmaf(-r3, r3, r3);
      float q0 = outv * (M0 * u0), q1 = outv * (M1 * u1);
      float q2 = outv * (M2 * u2), q3 = outv * (M3 * u3);
      v2f qa = {q0, q1}, qb = {q2, q3};
      aE += e; aW += outv;
      aQa += qa; aQb += qb;
      ORa += (v2f){outv * r0, outv * r1};
      ORb += (v2f){outv * r2, outv * r3};
#define G_UPD(k) if (ivc & (1u << k)) { g##k##a += qa; g##k##b += qb; }
      G_UPD(0) G_UPD(1) G_UPD(2) G_UPD(3) G_UPD(4) G_UPD(5) G_UPD(6)
#undef G_UPD
    }
    v2f aWHa = {aW - 2.0f * ORa.x, aW - 2.0f * ORa.y};
    v2f aWHb = {aW - 2.0f * ORb.x, aW - 2.0f * ORb.y};

    int lane = tx & 63;
    float rr;
    rr = dppsum64(aE); if (lane == 63 && rr != 0.0f) atomicAdd(&sS[0], rr);
    rr = dppsum64(aW); if (lane == 63 && rr != 0.0f) atomicAdd(&sS[1], rr);
    rr = dppsum64(aQa.x); if (lane == 63 && rr != 0.0f) atomicAdd(&sS[2], rr);
    rr = dppsum64(aQa.y); if (lane == 63 && rr != 0.0f) atomicAdd(&sS[3], rr);
    rr = dppsum64(aQb.x); if (lane == 63 && rr != 0.0f) atomicAdd(&sS[4], rr);
    rr = dppsum64(aQb.y); if (lane == 63 && rr != 0.0f) atomicAdd(&sS[5], rr);
    rr = dppsum64(aWHa.x); if (lane == 63 && rr != 0.0f) atomicAdd(&sS[6], rr);
    rr = dppsum64(aWHa.y); if (lane == 63 && rr != 0.0f) atomicAdd(&sS[7], rr);
    rr = dppsum64(aWHb.x); if (lane == 63 && rr != 0.0f) atomicAdd(&sS[8], rr);
    rr = dppsum64(aWHb.y); if (lane == 63 && rr != 0.0f) atomicAdd(&sS[9], rr);
#define GF(k) { \
    rr = dppsum64(g##k##a.x); if (lane == 63 && rr != 0.0f) atomicAdd(&sS[10 + 0 * 21 + k], rr); \
    rr = dppsum64(g##k##a.y); if (lane == 63 && rr != 0.0f) atomicAdd(&sS[10 + 1 * 21 + k], rr); \
    rr = dppsum64(g##k##b.x); if (lane == 63 && rr != 0.0f) atomicAdd(&sS[10 + 2 * 21 + k], rr); \
    rr = dppsum64(g##k##b.y); if (lane == 63 && rr != 0.0f) atomicAdd(&sS[10 + 3 * 21 + k], rr); }
    GF(0) GF(1) GF(2) GF(3) GF(4) GF(5) GF(6)
#undef GF
#pragma unroll
    for (int j = 0; j < 14; j++) {
      if (j < FS) {
        float m = (float)((pat >> j) & 1u);   // sentinel lanes have aQ==0
        rr = dppsum64(m * aQa.x); if (lane == 63 && rr != 0.0f) atomicAdd(&sS[10 + 0 * 21 + FBE + j], rr);
        rr = dppsum64(m * aQa.y); if (lane == 63 && rr != 0.0f) atomicAdd(&sS[10 + 1 * 21 + FBE + j], rr);
        rr = dppsum64(m * aQb.x); if (lane == 63 && rr != 0.0f) atomicAdd(&sS[10 + 2 * 21 + FBE + j], rr);
        rr = dppsum64(m * aQb.y); if (lane == 63 && rr != 0.0f) atomicAdd(&sS[10 + 3 * 21 + FBE + j], rr);
      }
    }
  }
  __syncthreads();
  if (tx < SUMS_STRIDE) {
    float v = sS[tx];
    if (v != 0.0f) gatomic(&ws[OFF_SUMS + t * SUMS_STRIDE + tx], v);
  }
}

__global__ __launch_bounds__(BT) void kc(
    const float* W2_2, const float* b2_2,
    const float* W2_3, const float* b2_3,
    float* ws) {
  __shared__ float4 tabL[384];
  __shared__ float sS[SUMS_STRIDE];
  int b = blockIdx.x;
  int t, sub;
  if (b < NSTEP2 * KC_B2) { t = b / KC_B2; sub = b % KC_B2; }
  else { int b3 = b - NSTEP2 * KC_B2; t = NSTEP2 + b3 / KC_B3; sub = b3 % KC_B3; }
  int rep = ((const int*)ws)[OFF_REP + t];
  if (rep != t) return;   // only representative steps enumerate
  if (t < NSTEP2) {
    int set = (t == 0) ? 0 : 1;
    kc_work<21>(t, sub, set, W2_2, b2_2, ws, tabL, sS);
  } else {
    kc_work<20>(t, sub, 2, W2_3, b2_3, ws, tabL, sS);
  }
}

// =================== Kernel D: p-chain + finalize gradient outputs ===================
__global__ __launch_bounds__(256) void kd(const float* p0in,
                   const float* W1_2, const float* b1_2, const float* W2_2, const float* b2_2,
                   const float* W1_3, const float* b1_3, const float* W2_3, const float* b2_3,
                   const float* ws, float* out) {
  __shared__ float sS[NSTEPS * SUMS_STRIDE];   // 12 KB
  __shared__ float sKEYB[128], sW1c0[8], sW2[8], sB2[2];
  __shared__ float sk_s[NSTEPS][4], hk_s[NSTEPS][4], pp_s[NSTEPS], s0i_s[NSTEPS];
  __shared__ int sREP[NSTEPS];
  int tx = threadIdx.x;
  for (int i = tx; i < NSTEPS * SUMS_STRIDE; i += 256) sS[i] = ws[OFF_SUMS + i];
  for (int i = tx; i < 128; i += 256) sKEYB[i] = ws[OFF_KEYB + i];
  if (tx < NSTEPS) sREP[tx] = ((const int*)ws)[OFF_REP + tx];
  if (tx < 4) {
    sW1c0[tx]     = W1_2[tx * (L2 + 1)];
    sW1c0[4 + tx] = W1_3[tx * (L3 + 1)];
    sW2[tx]     = W2_2[tx];
    sW2[4 + tx] = W2_3[tx];
  }
  if (tx == 0) { sB2[0] = b2_2[0]; sB2[1] = b2_3[0]; }
  __syncthreads();
  if (tx == 0) {
    float p = p0in[0];
    out[0] = p;
    for (int t = 0; t < NSTEPS; t++) {
      int g = (t < NSTEP2) ? 0 : 1;
      pp_s[t] = p;
      float outk = sB2[g];
      for (int h = 0; h < 4; h++)
        outk += sW2[g * 4 + h] * fast_tanh(sKEYB[t * 4 + h] + p * sW1c0[g * 4 + h]);
      float Se = sS[sREP[t] * SUMS_STRIDE + 0];
      p = fast_exp(outk) / Se;
      out[1 + t] = p;
    }
  }
  __syncthreads();
  if (tx < NSTEPS) {
    int t = tx; int g = (t < NSTEP2) ? 0 : 1;
    float p = pp_s[t];
    s0i_s[t] = 1.0f / sS[sREP[t] * SUMS_STRIDE + 0];
    for (int h = 0; h < 4; h++) {
      float hk = fast_tanh(sKEYB[t * 4 + h] + p * sW1c0[g * 4 + h]);
      hk_s[t][h] = hk;
      sk_s[t][h] = (1.0f - hk * hk) * sW2[g * 4 + h];
    }
  }
  __syncthreads();
  const unsigned* cbp = (const unsigned*)ws;
  for (int o = 33 + tx; o < 223; o += blockDim.x) {
    float val = 0.0f;
    if (o < 130) {
      if (o < 121) {
        int e = o - 33; int h = e / 22, d = e % 22;
        for (int t = 0; t < NSTEP2; t++) {
          int rp = sREP[t];
          float xk = (d == 0) ? pp_s[t] : (float)((cbp[OFF_CB + t] >> (d - 1)) & 1);
          float gs = (d == 0) ? pp_s[t] * sS[rp * SUMS_STRIDE + 2 + h]
                              : sS[rp * SUMS_STRIDE + 10 + h * 21 + (d - 1)];
          val += sk_s[t][h] * xk - gs * s0i_s[t];
        }
      } else if (o < 125) { int h = o - 121;
        for (int t = 0; t < NSTEP2; t++) val += sk_s[t][h] - sS[sREP[t] * SUMS_STRIDE + 2 + h] * s0i_s[t];
      } else if (o < 129) { int h = o - 125;
        for (int t = 0; t < NSTEP2; t++) val += hk_s[t][h] - sS[sREP[t] * SUMS_STRIDE + 6 + h] * s0i_s[t];
      } else {
        for (int t = 0; t < NSTEP2; t++) val += 1.0f - sS[sREP[t] * SUMS_STRIDE + 1] * s0i_s[t];
      }
    } else {
      if (o < 214) {
        int e = o - 130; int h = e / 21, d = e % 21;
        for (int t = NSTEP2; t < NSTEPS; t++) {
          int rp = sREP[t];
          float xk = (d == 0) ? pp_s[t] : (float)((cbp[OFF_CB + t] >> (d - 1)) & 1);
          float gs = (d == 0) ? pp_s[t] * sS[rp * SUMS_STRIDE + 2 + h]
                              : sS[rp * SUMS_STRIDE + 10 + h * 21 + (d - 1)];
          val += sk_s[t][h] * xk - gs * s0i_s[t];
        }
      } else if (o < 218) { int h = o - 214;
        for (int t = NSTEP2; t < NSTEPS; t++) val += sk_s[t][h] - sS[sREP[t] * SUMS_STRIDE + 2 + h] * s0i_s[t];
      } else if (o < 222) { int h = o - 218;
        for (int t = NSTEP2; t < NSTEPS; t++) val += hk_s[t][h] - sS[sREP[t] * SUMS_STRIDE + 6 + h] * s0i_s[t];
      } else {
        for (int t = NSTEP2; t < NSTEPS; t++) val += 1.0f - sS[sREP[t] * SUMS_STRIDE + 1] * s0i_s[t];
      }
    }
    out[o] = val;
  }
}

extern "C" void kernel_launch(void* const* d_in, const int* in_sizes, int n_in,
                              void* d_out, int out_size, void* d_ws, size_t ws_size,
                              hipStream_t stream) {
  const float* p0   = (const float*)d_in[0];
  const float* sel  = (const float*)d_in[1];
  const float* W1_2 = (const float*)d_in[2]; const float* b1_2 = (const float*)d_in[3];
  const float* W2_2 = (const float*)d_in[4]; const float* b2_2 = (const float*)d_in[5];
  const float* W1_3 = (const float*)d_in[6]; const float* b1_3 = (const float*)d_in[7];
  const float* W2_3 = (const float*)d_in[8]; const float* b2_3 = (const float*)d_in[9];
  float* out = (float*)d_out;
  float* ws  = (float*)d_ws;
  hipLaunchKernelGGL(kz, dim3(4 + (NPAT2P + NPAT3P + 255) / 256), dim3(256), 0, stream,
                     p0, sel, W1_2, b1_2, W1_3, b1_3, ws);
  hipLaunchKernelGGL(kc, dim3(KC_BLOCKS), dim3(BT), 0, stream,
                     W2_2, b2_2, W2_3, b2_3, ws);
  hipLaunchKernelGGL(kd, dim3(1), dim3(256), 0, stream, p0,
                     W1_2, b1_2, W2_2, b2_2, W1_3, b1_3, W2_3, b2_3, ws, out);
}